// Round 6
// baseline (100.842 us; speedup 1.0000x reference)
//
#include <hip/hip_runtime.h>

// out[b, o*8+n, h, w] = sum_k W[o,k] * x[b, n*32+k, h, w]
// B=32, C=512, HW=3136, 8 windows (stride 32, width 64), W is 64x64 f32.
//
// Per (b,n): C[64 x 3136] = W[64x64] . X[64 x 3136] via bf16 MFMA 32x32x16.
// Block = 128 threads = 2 waves sharing one 64-pixel strip; wave mw owns
// output-channel half m = mw (rows mw*32..mw*32+31). Halves VGPR vs the
// round-5 single-wave kernel (acc 64->32, afrag 32->16) -> 4 waves/SIMD.
// Both waves load the same x float2s concurrently on the same CU (L1/MSHR
// merge); HBM traffic unchanged.
//
// 64-pixel strip as TWO interleaved 32-col tiles: tile t, col c <-> pixel
// p0 + 2c + t; lane lc's float2 load feeds tile0 (.x) / tile1 (.y).
//
// Fragment mappings (verified by round-3/5 passes, absmax 0.0156):
//   A: lane l, elem j holds W[mw*32 + (l&31)][s*16 + (l>>5)*8 + j]
//   B: lane l, elem j holds x[ch = n*32 + s*16 + (l>>5)*8 + j][pixel(col=l&31)]
//   C: col = lane&31, row = (reg&3) + 8*(reg>>2) + 4*(lane>>5)

#define HW   3136
#define CHW  (512 * HW)

typedef float  f32x16 __attribute__((ext_vector_type(16)));
typedef float  f32x2  __attribute__((ext_vector_type(2)));
typedef __bf16 bf16x8 __attribute__((ext_vector_type(8)));

__global__ __launch_bounds__(128, 4) void SKC_65841848648481_kernel(
    const float* __restrict__ x,
    const float* __restrict__ w,
    float* __restrict__ out)
{
    const int lane = threadIdx.x & 63;
    const int mw   = threadIdx.x >> 6;      // M-half owned by this wave (0/1)
    const int lc   = lane & 31;
    const int lh   = lane >> 5;

    // Bijective XCD swizzle: 12544 work-ids, 12544 % 8 == 0, 1568 contiguous
    // ids per XCD -> window-overlap re-reads stay in that XCD's L2.
    int id = blockIdx.x;
    id = (id & 7) * 1568 + (id >> 3);
    const int strip = id % 49;              // 64-px strip within (b,n)
    const int n     = (id / 49) & 7;        // window 0..7
    const int b     = id / 392;             // batch 0..31
    const int p0    = strip * 64;

    // ---- W -> A fragments for this wave's M-half ----
    bf16x8 afrag[4];
    {
        const float* wr = w + (mw * 32 + lc) * 64;
        #pragma unroll
        for (int s = 0; s < 4; ++s) {
            const float4 w0 = *(const float4*)(wr + s * 16 + lh * 8);
            const float4 w1 = *(const float4*)(wr + s * 16 + lh * 8 + 4);
            bf16x8 a;
            a[0] = (__bf16)w0.x; a[1] = (__bf16)w0.y;
            a[2] = (__bf16)w0.z; a[3] = (__bf16)w0.w;
            a[4] = (__bf16)w1.x; a[5] = (__bf16)w1.y;
            a[6] = (__bf16)w1.z; a[7] = (__bf16)w1.w;
            afrag[s] = a;
        }
    }

    // ---- X gather: float2 per (s,j) at pixels p0+2lc, p0+2lc+1 of channel
    //      ch = n*32 + s*16 + lh*8 + j  (max 287 < 512, in-bounds) ----
    const float* xp = x + (size_t)b * CHW + (size_t)(n * 32 + lh * 8) * HW + p0 + 2 * lc;
    f32x2 xv[4][8];
    #pragma unroll
    for (int s = 0; s < 4; ++s) {
        #pragma unroll
        for (int j = 0; j < 8; ++j) {
            xv[s][j] = *(const f32x2*)(xp + (size_t)(s * 16 + j) * HW);
        }
    }

    // ---- pack B fragments ----
    bf16x8 bfrag[2][4];
    #pragma unroll
    for (int s = 0; s < 4; ++s) {
        bf16x8 b0, b1;
        #pragma unroll
        for (int j = 0; j < 8; ++j) {
            b0[j] = (__bf16)xv[s][j].x;
            b1[j] = (__bf16)xv[s][j].y;
        }
        bfrag[0][s] = b0;
        bfrag[1][s] = b1;
    }

    // ---- MFMA: acc[t] += A[s] * B[t][s] (this wave's M-half only) ----
    f32x16 acc[2];
    #pragma unroll
    for (int t = 0; t < 2; ++t)
        #pragma unroll
        for (int r = 0; r < 16; ++r)
            acc[t][r] = 0.0f;

    #pragma unroll
    for (int s = 0; s < 4; ++s) {
        acc[0] = __builtin_amdgcn_mfma_f32_32x32x16_bf16(
            afrag[s], bfrag[0][s], acc[0], 0, 0, 0);
        acc[1] = __builtin_amdgcn_mfma_f32_32x32x16_bf16(
            afrag[s], bfrag[1][s], acc[1], 0, 0, 0);
    }

    // ---- store: channel (mw*32+row)*8 + n, pixels p0+2lc (+1) ----
    float* op = out + (size_t)b * CHW + (size_t)n * HW + p0 + 2 * lc;
    #pragma unroll
    for (int r = 0; r < 16; ++r) {
        const int row = (r & 3) + 8 * (r >> 2) + 4 * lh;
        f32x2 v;
        v.x = acc[0][r];
        v.y = acc[1][r];
        *(f32x2*)(op + (size_t)((mw * 32 + row) * 8) * HW) = v;
    }
}

extern "C" void kernel_launch(void* const* d_in, const int* in_sizes, int n_in,
                              void* d_out, int out_size, void* d_ws, size_t ws_size,
                              hipStream_t stream)
{
    const float* x  = (const float*)d_in[0];   // (32, 512, 56, 56) f32
    const float* w  = (const float*)d_in[1];   // (64, 64) f32
    float* out      = (float*)d_out;           // (32, 512, 56, 56) f32

    dim3 grid(49 * 8 * 32);   // one block (2 waves) per 64-px strip
    dim3 block(128);
    hipLaunchKernelGGL(SKC_65841848648481_kernel, grid, block, 0, stream,
                       x, w, out);
}